// Round 3
// baseline (3671.584 us; speedup 1.0000x reference)
//
#include <hip/hip_runtime.h>

#define NNODES 60000
#define NPAD   60032
#define NBLK   469      // NPAD/128
#define NEDGES 150000
#define NGRAPH 2048
#define DIM    512
#define NLAYER 5

typedef unsigned short u16;
typedef unsigned int   u32;
typedef __attribute__((ext_vector_type(8))) short s16x8;
typedef __attribute__((ext_vector_type(4))) float f32x4;

__device__ __forceinline__ float b2f(u16 u){ u32 x=(u32)u<<16; return __builtin_bit_cast(float,x); }
__device__ __forceinline__ u16 f2b(float f){ u32 x=__builtin_bit_cast(u32,f); x += 0x7FFFu + ((x>>16)&1u); return (u16)(x>>16); }

// ---------------- transpose fp32 KxN -> bf16 NxK (hi plane, optional lo plane) ----------------
__global__ void transpose_bt(const float* __restrict__ W, u16* __restrict__ Wt,
                             u16* __restrict__ WtLo, int K, int N, int wantLo){
  __shared__ float tile[32][33];
  int bx=blockIdx.x*32, by=blockIdx.y*32;
  int tx=threadIdx.x&31, ty=threadIdx.x>>5;
  for(int i=ty;i<32;i+=8) tile[i][tx]=W[(size_t)(by+i)*N + bx+tx];
  __syncthreads();
  for(int i=ty;i<32;i+=8){
    float v=tile[tx][i];
    u16 hi=f2b(v);
    size_t o=(size_t)(bx+i)*K + by+tx;
    Wt[o]=hi;
    if(wantLo) WtLo[o]=f2b(v-b2f(hi));
  }
}

// ---------------- dense K=40 -> 512, relu, split bf16 out ----------------
__global__ void dense40(const float* __restrict__ X, const float* __restrict__ W,
                        const float* __restrict__ b, u16* __restrict__ Y,
                        u16* __restrict__ Ylo, int wantLo, int M, int Mpad){
  __shared__ float xs[64];
  int t=threadIdx.x;
  int c0=2*t;
  float w0[40], w1[40];
  #pragma unroll
  for(int k=0;k<40;++k){ w0[k]=W[k*DIM+c0]; w1[k]=W[k*DIM+c0+1]; }
  float bb0=b[c0], bb1=b[c0+1];
  for(int m=blockIdx.x;m<Mpad;m+=gridDim.x){
    size_t o=(size_t)m*DIM+c0;
    if(m<M){
      if(t<40) xs[t]=X[m*40+t];
      __syncthreads();
      float a0=bb0, a1=bb1;
      #pragma unroll
      for(int k=0;k<40;++k){ float xv=xs[k]; a0+=xv*w0[k]; a1+=xv*w1[k]; }
      a0=fmaxf(a0,0.f); a1=fmaxf(a1,0.f);
      u16 h0=f2b(a0), h1=f2b(a1);
      *(u32*)&Y[o]=(u32)h0|((u32)h1<<16);
      if(wantLo) *(u32*)&Ylo[o]=(u32)f2b(a0-b2f(h0))|((u32)f2b(a1-b2f(h1))<<16);
      __syncthreads();
    } else {
      *(u32*)&Y[o]=0u;
      if(wantLo) *(u32*)&Ylo[o]=0u;
    }
  }
}

// ---------------- CSR build ----------------
__global__ void hist_kernel(const int* __restrict__ idx, int* __restrict__ cnt, int n){
  int i=blockIdx.x*256+threadIdx.x;
  if(i<n) atomicAdd(&cnt[idx[i]],1);
}

__global__ void scan_excl(const int* __restrict__ in, int* __restrict__ out, int n){
  __shared__ int buf[1024];
  __shared__ int carry;
  if(threadIdx.x==0){ carry=0; out[0]=0; }
  __syncthreads();
  for(int base=0;base<n;base+=1024){
    int i=base+threadIdx.x;
    int v=(i<n)?in[i]:0;
    buf[threadIdx.x]=v;
    __syncthreads();
    for(int off=1;off<1024;off<<=1){
      int add=(threadIdx.x>=off)?buf[threadIdx.x-off]:0;
      __syncthreads();
      buf[threadIdx.x]+=add;
      __syncthreads();
    }
    if(i<n) out[i+1]=carry+buf[threadIdx.x];
    __syncthreads();
    if(threadIdx.x==1023) carry+=buf[1023];
    __syncthreads();
  }
}

__global__ void scatter_edges(const int* __restrict__ eidx, const int* __restrict__ eattr,
                              const int* __restrict__ rowptr, int* __restrict__ cnt,
                              u32* __restrict__ es_pk){
  int e=blockIdx.x*256+threadIdx.x;
  if(e>=NEDGES) return;
  int s=eidx[e], d=eidx[NEDGES+e];
  int pos=rowptr[d]+atomicAdd(&cnt[d],1);
  es_pk[pos]=(u32)s | ((u32)(eattr[2*e]*3+eattr[2*e+1])<<16);
}

__global__ void scatter_batch(const int* __restrict__ batch, const int* __restrict__ browptr,
                              int* __restrict__ bcnt, u16* __restrict__ bnodes){
  int n=blockIdx.x*256+threadIdx.x;
  if(n>=NNODES) return;
  int g=batch[n];
  int pos=browptr[g]+atomicAdd(&bcnt[g],1);
  bnodes[pos]=(u16)n;
}

// ---- aggregate rows [n0,n1): agg = h[n]+self_emb + sum_e (h[src]+emb(combo)); split out ----
__global__ void agg_kernel(const u16* __restrict__ hh, const u16* __restrict__ hl, int hL,
    const int* __restrict__ rowptr, const u32* __restrict__ es_pk,
    const float* __restrict__ emb1, const float* __restrict__ emb2,
    u16* __restrict__ ah, u16* __restrict__ al, int n0, int n1){
  __shared__ float combo[10][DIM];
  for(int i=threadIdx.x;i<10*DIM;i+=256){
    int c=i>>9, d=i&(DIM-1);
    int bt=(c<9)?(c/3):4, bd=(c<9)?(c%3):0;
    combo[c][d]=emb1[bt*DIM+d]+emb2[bd*DIM+d];
  }
  __syncthreads();
  int c0=2*threadIdx.x;
  for(int n=n0+blockIdx.x;n<n1;n+=gridDim.x){
    float a0,a1;
    if(n<NNODES){
      size_t ix=(size_t)n*DIM+c0;
      u32 hv=*(const u32*)&hh[ix];
      a0=b2f((u16)hv)+combo[9][c0];
      a1=b2f((u16)(hv>>16))+combo[9][c0+1];
      if(hL){ u32 lv=*(const u32*)&hl[ix]; a0+=b2f((u16)lv); a1+=b2f((u16)(lv>>16)); }
      int pe=rowptr[n+1];
      for(int p=rowptr[n];p<pe;++p){
        u32 pk=es_pk[p];
        int s=pk&0xFFFF, c=pk>>16;
        size_t sx=(size_t)s*DIM+c0;
        u32 sv=*(const u32*)&hh[sx];
        a0+=b2f((u16)sv)+combo[c][c0];
        a1+=b2f((u16)(sv>>16))+combo[c][c0+1];
        if(hL){ u32 lv=*(const u32*)&hl[sx]; a0+=b2f((u16)lv); a1+=b2f((u16)(lv>>16)); }
      }
    } else { a0=0.f; a1=0.f; }
    size_t o=(size_t)(n-n0)*DIM+c0;
    u16 h0=f2b(a0), h1=f2b(a1);
    *(u32*)&ah[o]=(u32)h0|((u32)h1<<16);
    *(u32*)&al[o]=(u32)f2b(a0-b2f(h0))|((u32)f2b(a1-b2f(h1))<<16);
  }
}

// ---- bf16 split-GEMM: C = act(A*B^T+bias); A/B optionally hi+lo planes; C optionally split ----
__global__ __launch_bounds__(256) void gemm_bt(
    const u16* __restrict__ Ah, const u16* __restrict__ Al,
    const u16* __restrict__ Bh, const u16* __restrict__ Bl,
    const float* __restrict__ bias, u16* __restrict__ Ch, u16* __restrict__ Cl,
    int K, int ldc, int aL, int bL, int cL, int relu)
{
  __shared__ u16 sm[4*128*64] __attribute__((aligned(16)));
  u16* Ash=sm; u16* Asl=sm+8192; u16* Bsh=sm+16384; u16* Bsl=sm+24576;
  int t=threadIdx.x, w=t>>6, l=t&63;
  size_t row0=(size_t)blockIdx.x*128, col0=(size_t)blockIdx.y*128;
  int wr=w>>1, wc=w&1;
  int lr=l&15, lk=(l>>4)*8;
  f32x4 acc[4][4]={};
  for(int k0=0;k0<K;k0+=64){
    #pragma unroll
    for(int i=0;i<4;++i){
      int c=i*256+t; int r=c>>3, c8=c&7;
      __builtin_amdgcn_global_load_lds(
        (const __attribute__((address_space(1))) void*)(Ah+(row0+r)*K+k0+c8*8),
        (__attribute__((address_space(3))) void*)(Ash+(size_t)(i*256+(w<<6))*8), 16,0,0);
      __builtin_amdgcn_global_load_lds(
        (const __attribute__((address_space(1))) void*)(Bh+(col0+r)*K+k0+c8*8),
        (__attribute__((address_space(3))) void*)(Bsh+(size_t)(i*256+(w<<6))*8), 16,0,0);
    }
    if(aL){
      #pragma unroll
      for(int i=0;i<4;++i){
        int c=i*256+t; int r=c>>3, c8=c&7;
        __builtin_amdgcn_global_load_lds(
          (const __attribute__((address_space(1))) void*)(Al+(row0+r)*K+k0+c8*8),
          (__attribute__((address_space(3))) void*)(Asl+(size_t)(i*256+(w<<6))*8), 16,0,0);
      }
    }
    if(bL){
      #pragma unroll
      for(int i=0;i<4;++i){
        int c=i*256+t; int r=c>>3, c8=c&7;
        __builtin_amdgcn_global_load_lds(
          (const __attribute__((address_space(1))) void*)(Bl+(col0+r)*K+k0+c8*8),
          (__attribute__((address_space(3))) void*)(Bsl+(size_t)(i*256+(w<<6))*8), 16,0,0);
      }
    }
    __syncthreads();
    #pragma unroll
    for(int kk=0;kk<2;++kk){
      s16x8 avh[4],bvh[4];
      #pragma unroll
      for(int m=0;m<4;++m) avh[m]=*(const s16x8*)(Ash+(wr*64+m*16+lr)*64+kk*32+lk);
      #pragma unroll
      for(int n=0;n<4;++n) bvh[n]=*(const s16x8*)(Bsh+(wc*64+n*16+lr)*64+kk*32+lk);
      #pragma unroll
      for(int m=0;m<4;++m)
        #pragma unroll
        for(int n=0;n<4;++n)
          acc[m][n]=__builtin_amdgcn_mfma_f32_16x16x32_bf16(avh[m],bvh[n],acc[m][n],0,0,0);
      if(aL){
        s16x8 avl[4];
        #pragma unroll
        for(int m=0;m<4;++m) avl[m]=*(const s16x8*)(Asl+(wr*64+m*16+lr)*64+kk*32+lk);
        #pragma unroll
        for(int m=0;m<4;++m)
          #pragma unroll
          for(int n=0;n<4;++n)
            acc[m][n]=__builtin_amdgcn_mfma_f32_16x16x32_bf16(avl[m],bvh[n],acc[m][n],0,0,0);
      }
      if(bL){
        s16x8 bvl[4];
        #pragma unroll
        for(int n=0;n<4;++n) bvl[n]=*(const s16x8*)(Bsl+(wc*64+n*16+lr)*64+kk*32+lk);
        #pragma unroll
        for(int m=0;m<4;++m)
          #pragma unroll
          for(int n=0;n<4;++n)
            acc[m][n]=__builtin_amdgcn_mfma_f32_16x16x32_bf16(avh[m],bvl[n],acc[m][n],0,0,0);
      }
    }
    __syncthreads();
  }
  #pragma unroll
  for(int n=0;n<4;++n){
    int col=(int)col0+wc*64+n*16+lr;
    float bcol=bias[col];
    #pragma unroll
    for(int m=0;m<4;++m){
      int rowb=(int)row0+wr*64+m*16+((l>>4)*4);
      #pragma unroll
      for(int r=0;r<4;++r){
        float v=acc[m][n][r]+bcol;
        if(relu) v=fmaxf(v,0.f);
        size_t off=(size_t)(rowb+r)*ldc+col;
        u16 hi=f2b(v);
        Ch[off]=hi;
        if(cL) Cl[off]=f2b(v-b2f(hi));
      }
    }
  }
}

// ---------------- BatchNorm ----------------
__global__ void bn_stats(const u16* __restrict__ h2h, const u16* __restrict__ h2l, int h2L,
                         float* __restrict__ stats){
  int t=threadIdx.x, c0=2*t;
  int r0=blockIdx.x*64;
  int r1=r0+64; if(r1>NNODES) r1=NNODES;
  float s0=0,s1=0,q0=0,q1=0;
  for(int r=r0;r<r1;++r){
    size_t ix=(size_t)r*DIM+c0;
    u32 v=*(const u32*)&h2h[ix];
    float x=b2f((u16)v), y=b2f((u16)(v>>16));
    if(h2L){ u32 lv=*(const u32*)&h2l[ix]; x+=b2f((u16)lv); y+=b2f((u16)(lv>>16)); }
    s0+=x; q0+=x*x; s1+=y; q1+=y*y;
  }
  atomicAdd(&stats[c0],s0); atomicAdd(&stats[c0+1],s1);
  atomicAdd(&stats[DIM+c0],q0); atomicAdd(&stats[DIM+c0+1],q1);
}

__global__ void bn_finalize(float* __restrict__ stats, const float* __restrict__ gamma,
                            const float* __restrict__ beta){
  int d=threadIdx.x;
  float mu=stats[d]*(1.f/NNODES);
  float var=stats[DIM+d]*(1.f/NNODES)-mu*mu;
  float sc=gamma[d]*rsqrtf(var+1e-5f);
  stats[2*DIM+d]=sc;
  stats[3*DIM+d]=beta[d]-mu*sc;
}

__global__ void bn_apply(const u16* __restrict__ h2h, const u16* __restrict__ h2l, int h2L,
    const float* __restrict__ stats, u16* __restrict__ hh, u16* __restrict__ hl, int hL, int relu){
  int idx=blockIdx.x*256+threadIdx.x;  // NNODES*64 threads, 8 elems each
  int d0=(idx&63)*8;
  size_t base=(size_t)idx*8;
  s16x8 v=*(const s16x8*)&h2h[base];
  s16x8 vl;
  if(h2L) vl=*(const s16x8*)&h2l[base];
  u16 oh[8], ol[8];
  #pragma unroll
  for(int j=0;j<8;++j){
    int d=d0+j;
    float x=b2f((u16)v[j]);
    if(h2L) x+=b2f((u16)vl[j]);
    x=x*stats[2*DIM+d]+stats[3*DIM+d];
    if(relu) x=fmaxf(x,0.f);
    u16 hi=f2b(x);
    oh[j]=hi; ol[j]=f2b(x-b2f(hi));
  }
  *(s16x8*)&hh[base]=*(const s16x8*)oh;
  if(hL) *(s16x8*)&hl[base]=*(const s16x8*)ol;
}

// ---------------- graph pooling ----------------
__global__ void batch_reduce(const u16* __restrict__ hh, const u16* __restrict__ hl, int hL,
    const int* __restrict__ browptr, const u16* __restrict__ bnodes,
    u16* __restrict__ zh, u16* __restrict__ zl, int zS){
  int g=blockIdx.x, t=threadIdx.x, c0=2*t;
  float a0=0,a1=0;
  int pe=browptr[g+1];
  for(int p=browptr[g];p<pe;++p){
    int n=bnodes[p];
    size_t ix=(size_t)n*DIM+c0;
    u32 v=*(const u32*)&hh[ix];
    a0+=b2f((u16)v); a1+=b2f((u16)(v>>16));
    if(hL){ u32 lv=*(const u32*)&hl[ix]; a0+=b2f((u16)lv); a1+=b2f((u16)(lv>>16)); }
  }
  size_t o=(size_t)g*1024+c0;
  u16 h0=f2b(a0), h1=f2b(a1);
  *(u32*)&zh[o]=(u32)h0|((u32)h1<<16);
  if(zS) *(u32*)&zl[o]=(u32)f2b(a0-b2f(h0))|((u32)f2b(a1-b2f(h1))<<16);
}

// ---------------- last layer: dot(128) + bias ----------------
__global__ void last_kernel(const u16* __restrict__ z2h, const u16* __restrict__ z2l, int zS,
    const float* __restrict__ lw, const float* __restrict__ lb, float* __restrict__ out){
  int g=blockIdx.x*4+(threadIdx.x>>6), l=threadIdx.x&63;
  float x0=b2f(z2h[g*128+l]), x1=b2f(z2h[g*128+64+l]);
  if(zS){ x0+=b2f(z2l[g*128+l]); x1+=b2f(z2l[g*128+64+l]); }
  float a=x0*lw[l]+x1*lw[64+l];
  #pragma unroll
  for(int off=32;off;off>>=1) a+=__shfl_down(a,off,64);
  if(l==0) out[g]=a+lb[0];
}

extern "C" void kernel_launch(void* const* d_in, const int* in_sizes, int n_in,
                              void* d_out, int out_size, void* d_ws, size_t ws_size,
                              hipStream_t stream){
  const float* solute_x =(const float*)d_in[0];
  const float* solvent_x=(const float*)d_in[1];
  const int*   eidx     =(const int*)d_in[2];
  const int*   eattr    =(const int*)d_in[3];
  const int*   batch    =(const int*)d_in[4];
  const float* xembW=(const float*)d_in[5];
  const float* xembB=(const float*)d_in[6];
  const float* m1W=(const float*)d_in[7];
  const float* m1b=(const float*)d_in[8];
  const float* m2W=(const float*)d_in[9];
  const float* m2b=(const float*)d_in[10];
  const float* ee1=(const float*)d_in[11];
  const float* ee2=(const float*)d_in[12];
  const float* gam=(const float*)d_in[13];
  const float* bet=(const float*)d_in[14];
  const float* sW1=(const float*)d_in[15];
  const float* sb1=(const float*)d_in[16];
  const float* sW2=(const float*)d_in[17];
  const float* sb2=(const float*)d_in[18];
  const float* oW0=(const float*)d_in[19];
  const float* ob0=(const float*)d_in[20];
  const float* oW1=(const float*)d_in[21];
  const float* ob1=(const float*)d_in[22];
  const float* oW2=(const float*)d_in[23];
  const float* ob2=(const float*)d_in[24];
  const float* lW =(const float*)d_in[25];
  const float* lb =(const float*)d_in[26];
  float* out=(float*)d_out;

  char* p=(char*)d_ws; size_t off=0;
  auto alloc=[&](size_t b)->void*{ void* q=p+off; off+=(b+255)&~(size_t)255; return q; };
  auto rem=[&]()->size_t{ return ws_size>off? ws_size-off:(size_t)0; };

  // ---- base (hi planes) ----
  u16* h_hi   =(u16*)alloc((size_t)NPAD*DIM*2);
  u16* h2_hi  =(u16*)alloc((size_t)NPAD*DIM*2);
  u16* W1t    =(u16*)alloc((size_t)NLAYER*1024*512*2);
  u16* W2t    =(u16*)alloc((size_t)NLAYER*512*1024*2);
  u16* sW2t   =(u16*)alloc((size_t)512*512*2);
  u16* oW0t   =(u16*)alloc((size_t)512*1024*2);
  u16* oW1t   =(u16*)alloc((size_t)256*512*2);
  u16* oW2t   =(u16*)alloc((size_t)128*256*2);
  u16* s1     =(u16*)alloc((size_t)NGRAPH*512*2);
  u16* z      =(u16*)alloc((size_t)NGRAPH*1024*2);
  u16* z0     =(u16*)alloc((size_t)NGRAPH*512*2);
  u16* z1     =(u16*)alloc((size_t)NGRAPH*256*2);
  u16* z2     =(u16*)alloc((size_t)NGRAPH*128*2);
  float* stats=(float*)alloc(4*DIM*4);
  int* rowptr =(int*)alloc((size_t)(NNODES+1)*4);
  int* degcnt =(int*)alloc((size_t)NNODES*4);      // deg, then reused as cnt
  u32* es_pk  =(u32*)alloc((size_t)NEDGES*4);
  int* bdeg   =(int*)alloc((size_t)NGRAPH*4);
  int* browptr=(int*)alloc((size_t)(NGRAPH+1)*4);
  int* bcnt   =(int*)alloc((size_t)NGRAPH*4);
  u16* bnodes =(u16*)alloc((size_t)NNODES*2);

  // ---- adaptive precision upgrades ----
  const size_t per_chb=(size_t)128*512*2*2 + (size_t)128*1024*2*2; // split agg + split t per 128-row blk
  const size_t RESERVE=per_chb+65536;
  size_t szSW =((size_t)512*512+512*1024+256*512+128*256)*2;
  size_t szRO =((size_t)NGRAPH*(512+1024+512+256+128))*2;
  size_t szW12=(size_t)NLAYER*(1024*512+512*1024)*2;
  size_t szH  =(size_t)NPAD*DIM*2;
  size_t BOOST=(size_t)60*per_chb;

  u16 *sW2tL=0,*oW0tL=0,*oW1tL=0,*oW2tL=0, *s1L=0,*zL=0,*z0L=0,*z1L=0,*z2L=0;
  u16 *W1tL=0,*W2tL=0,*h2_lo=0,*h_lo=0;
  int wSL=0, rS=0, w12L=0, h2L=0, hL=0;
  if(rem()>=szSW+RESERVE){ wSL=1;
    sW2tL=(u16*)alloc((size_t)512*512*2); oW0tL=(u16*)alloc((size_t)512*1024*2);
    oW1tL=(u16*)alloc((size_t)256*512*2); oW2tL=(u16*)alloc((size_t)128*256*2); }
  if(rem()>=szRO+RESERVE){ rS=1;
    s1L=(u16*)alloc((size_t)NGRAPH*512*2); zL=(u16*)alloc((size_t)NGRAPH*1024*2);
    z0L=(u16*)alloc((size_t)NGRAPH*512*2); z1L=(u16*)alloc((size_t)NGRAPH*256*2);
    z2L=(u16*)alloc((size_t)NGRAPH*128*2); }
  if(rem()>=szW12+RESERVE){ w12L=1;
    W1tL=(u16*)alloc((size_t)NLAYER*1024*512*2); W2tL=(u16*)alloc((size_t)NLAYER*512*1024*2); }
  if(rem()>=szH+BOOST+65536){ h2L=1; h2_lo=(u16*)alloc(szH); }
  if(rem()>=szH+BOOST+65536){ hL=1;  h_lo =(u16*)alloc(szH); }

  size_t left = rem()>4096 ? rem()-4096 : 0;
  int chb=(int)(left/per_chb);
  if(chb<1) return;            // cannot fit one chunk: launch nothing (diagnostic)
  if(chb>NBLK) chb=NBLK;
  u16* agg_h=(u16*)alloc((size_t)chb*128*512*2);
  u16* agg_l=(u16*)alloc((size_t)chb*128*512*2);
  u16* t_h  =(u16*)alloc((size_t)chb*128*1024*2);
  u16* t_l  =(u16*)alloc((size_t)chb*128*1024*2);

  // ---- weight transposes ----
  for(int l=0;l<NLAYER;++l){
    transpose_bt<<<dim3(32,16),256,0,stream>>>(m1W+(size_t)l*512*1024, W1t+(size_t)l*1024*512,
                                               w12L? W1tL+(size_t)l*1024*512:0, 512,1024, w12L);
    transpose_bt<<<dim3(16,32),256,0,stream>>>(m2W+(size_t)l*1024*512, W2t+(size_t)l*512*1024,
                                               w12L? W2tL+(size_t)l*512*1024:0, 1024,512, w12L);
  }
  transpose_bt<<<dim3(16,16),256,0,stream>>>(sW2, sW2t, sW2tL, 512,512, wSL);
  transpose_bt<<<dim3(16,32),256,0,stream>>>(oW0, oW0t, oW0tL, 1024,512, wSL);
  transpose_bt<<<dim3(8,16),256,0,stream>>>(oW1, oW1t, oW1tL, 512,256, wSL);
  transpose_bt<<<dim3(4,8),256,0,stream>>>(oW2, oW2t, oW2tL, 256,128, wSL);

  // ---- embed ----
  dense40<<<2048,256,0,stream>>>(solute_x, xembW, xembB, h_hi, h_lo, hL, NNODES, NPAD);

  // ---- edge CSR ----
  hipMemsetAsync(degcnt,0,(size_t)NNODES*4,stream);
  hist_kernel<<<(NEDGES+255)/256,256,0,stream>>>(eidx+NEDGES, degcnt, NEDGES);
  scan_excl<<<1,1024,0,stream>>>(degcnt, rowptr, NNODES);
  hipMemsetAsync(degcnt,0,(size_t)NNODES*4,stream);
  scatter_edges<<<(NEDGES+255)/256,256,0,stream>>>(eidx, eattr, rowptr, degcnt, es_pk);

  // ---- batch CSR ----
  hipMemsetAsync(bdeg,0,(size_t)NGRAPH*4,stream);
  hist_kernel<<<(NNODES+255)/256,256,0,stream>>>(batch, bdeg, NNODES);
  scan_excl<<<1,1024,0,stream>>>(bdeg, browptr, NGRAPH);
  hipMemsetAsync(bcnt,0,(size_t)NGRAPH*4,stream);
  scatter_batch<<<(NNODES+255)/256,256,0,stream>>>(batch, browptr, bcnt, bnodes);

  // ---- GNN layers ----
  for(int l=0;l<NLAYER;++l){
    const float* e1=ee1+(size_t)l*6*DIM;
    const float* e2=ee2+(size_t)l*3*DIM;
    for(int b0=0;b0<NBLK;b0+=chb){
      int nb=NBLK-b0; if(nb>chb) nb=chb;
      int n0=b0*128, rows=nb*128;
      int g=rows<2048?rows:2048;
      agg_kernel<<<g,256,0,stream>>>(h_hi,h_lo,hL, rowptr, es_pk, e1, e2, agg_h, agg_l, n0, n0+rows);
      gemm_bt<<<dim3(nb,8),256,0,stream>>>(agg_h, agg_l, W1t+(size_t)l*1024*512,
          w12L? W1tL+(size_t)l*1024*512:0, m1b+(size_t)l*1024, t_h, t_l,
          512, 1024, 1, w12L, 1, 1);
      gemm_bt<<<dim3(nb,4),256,0,stream>>>(t_h, t_l, W2t+(size_t)l*512*1024,
          w12L? W2tL+(size_t)l*512*1024:0, m2b+(size_t)l*512,
          h2_hi+(size_t)n0*DIM, h2L? h2_lo+(size_t)n0*DIM:0,
          1024, 512, 1, w12L, h2L, 0);
    }
    hipMemsetAsync(stats,0,2*DIM*4,stream);
    bn_stats<<<(NNODES+63)/64,256,0,stream>>>(h2_hi,h2_lo,h2L, stats);
    bn_finalize<<<1,512,0,stream>>>(stats, gam+(size_t)l*DIM, bet+(size_t)l*DIM);
    bn_apply<<<(NNODES*64)/256,256,0,stream>>>(h2_hi,h2_lo,h2L, stats, h_hi,h_lo,hL, (l<NLAYER-1)?1:0);
  }

  // ---- pooling + solvent + readout ----
  batch_reduce<<<NGRAPH,256,0,stream>>>(h_hi,h_lo,hL, browptr, bnodes, z, zL, rS);
  dense40<<<2048,256,0,stream>>>(solvent_x, sW1, sb1, s1, s1L, rS, NGRAPH, NGRAPH);
  gemm_bt<<<dim3(16,4),256,0,stream>>>(s1, s1L, sW2t, sW2tL, sb2, z+512, rS? zL+512:0,
                                       512, 1024, rS, wSL, rS, 0);
  gemm_bt<<<dim3(16,4),256,0,stream>>>(z, zL, oW0t, oW0tL, ob0, z0, z0L, 1024, 512, rS, wSL, rS, 1);
  gemm_bt<<<dim3(16,2),256,0,stream>>>(z0, z0L, oW1t, oW1tL, ob1, z1, z1L, 512, 256, rS, wSL, rS, 1);
  gemm_bt<<<dim3(16,1),256,0,stream>>>(z1, z1L, oW2t, oW2tL, ob2, z2, z2L, 256, 128, rS, wSL, rS, 1);
  last_kernel<<<NGRAPH/4,256,0,stream>>>(z2, z2L, rS, lW, lb, out);
}